// Round 12
// baseline (718.544 us; speedup 1.0000x reference)
//
#include <hip/hip_runtime.h>

#define E_N 100000
#define NDST 234000   // concatenated per-type dst index space

typedef __attribute__((ext_vector_type(8))) short bfrag8;
typedef __attribute__((ext_vector_type(4))) float accf4;

__device__ __forceinline__ void atomAddF(float* p, float v) { unsafeAtomicAdd(p, v); }
__device__ __forceinline__ float lrelu(float v) { return v >= 0.f ? v : 0.2f * v; }

__device__ __forceinline__ unsigned short f2bf(float f) {
    unsigned u = __float_as_uint(f);
    return (unsigned short)((u + 0x7FFFu + ((u >> 16) & 1u)) >> 16);
}
__device__ __forceinline__ float bf2f(unsigned short h) {
    return __uint_as_float(((unsigned)h) << 16);
}

__constant__ int c_tbase[8] = {0, 1000, 51000, 71000, 121000, 126000, 176000, 184000};
__constant__ int c_co4[4]   = {0, 1000, 21000, 26000};

struct EI8 { const int* p[8]; };

struct BTJob { const float* W; unsigned short* hi; unsigned short* lo; int K; int kshift; };
struct BTBatch { BTJob j[17]; };

struct MJob { const float* A; const unsigned short* BThi; const unsigned short* BTlo;
              float* C; unsigned short* Cbf; const float* bias; int M; int K; int relu; };
struct MBatch { MJob j[8]; };

// ---------------- MFMA split-bf16 GEMM body (128x128 tile, paired-half decode) -------
__device__ __forceinline__ void gemm_body(const MJob jb, int bx)
{
    const int rowblk = (bx >> 4) * 8 + (bx & 7);
    const int half = (bx >> 3) & 1;
    const int bm = rowblk * 128;
    if (bm >= jb.M) return;
    const int bn = half * 128;
    const int M = jb.M, K = jb.K;

    __shared__ unsigned short Ah[128 * 40];
    __shared__ unsigned short Al[128 * 40];
    __shared__ unsigned short B1[128 * 40];
    __shared__ unsigned short B2[128 * 40];

    const int tid  = threadIdx.x;
    const int wv   = tid >> 6;
    const int lane = tid & 63;
    const int qr = wv >> 1, qc = wv & 1;
    const int lm = lane & 15;
    const int lq = lane >> 4;

    accf4 acc[4][4] = {};

    for (int k0 = 0; k0 < K; k0 += 32) {
#pragma unroll
        for (int it = 0; it < 4; ++it) {
            int slot = it * 256 + tid;
            int m  = slot >> 3;
            int kq = (slot & 7) << 2;
            float4 v = make_float4(0.f, 0.f, 0.f, 0.f);
            if (bm + m < M) v = *(const float4*)(jb.A + (size_t)(bm + m) * K + k0 + kq);
            int o = m * 40 + kq;
            unsigned short h0 = f2bf(v.x), h1 = f2bf(v.y), h2 = f2bf(v.z), h3 = f2bf(v.w);
            Ah[o + 0] = h0; Ah[o + 1] = h1; Ah[o + 2] = h2; Ah[o + 3] = h3;
            Al[o + 0] = f2bf(v.x - bf2f(h0));
            Al[o + 1] = f2bf(v.y - bf2f(h1));
            Al[o + 2] = f2bf(v.z - bf2f(h2));
            Al[o + 3] = f2bf(v.w - bf2f(h3));
        }
#pragma unroll
        for (int it = 0; it < 2; ++it) {
            int slot = it * 256 + tid;
            int n  = slot >> 2;
            int kq = (slot & 3) << 3;
            size_t go = (size_t)(bn + n) * K + k0 + kq;
            *(uint4*)&B1[n * 40 + kq] = *(const uint4*)(jb.BThi + go);
            *(uint4*)&B2[n * 40 + kq] = *(const uint4*)(jb.BTlo + go);
        }
        __syncthreads();

        bfrag8 ah[4], al[4], b1[4], b2[4];
#pragma unroll
        for (int t = 0; t < 4; ++t) {
            int am  = qr * 64 + t * 16 + lm;
            int bnn = qc * 64 + t * 16 + lm;
            ah[t] = *(const bfrag8*)&Ah[am * 40 + lq * 8];
            al[t] = *(const bfrag8*)&Al[am * 40 + lq * 8];
            b1[t] = *(const bfrag8*)&B1[bnn * 40 + lq * 8];
            b2[t] = *(const bfrag8*)&B2[bnn * 40 + lq * 8];
        }
#pragma unroll
        for (int mt = 0; mt < 4; ++mt)
#pragma unroll
            for (int nt = 0; nt < 4; ++nt) {
                acc[mt][nt] = __builtin_amdgcn_mfma_f32_16x16x32_bf16(ah[mt], b1[nt], acc[mt][nt], 0, 0, 0);
                acc[mt][nt] = __builtin_amdgcn_mfma_f32_16x16x32_bf16(al[mt], b1[nt], acc[mt][nt], 0, 0, 0);
                acc[mt][nt] = __builtin_amdgcn_mfma_f32_16x16x32_bf16(ah[mt], b2[nt], acc[mt][nt], 0, 0, 0);
            }
        __syncthreads();
    }

#pragma unroll
    for (int nt = 0; nt < 4; ++nt) {
        int col = bn + qc * 64 + nt * 16 + lm;
        float bv = jb.bias ? jb.bias[col] : 0.f;
#pragma unroll
        for (int mt = 0; mt < 4; ++mt) {
            int row0 = bm + qr * 64 + mt * 16 + lq * 4;
#pragma unroll
            for (int r = 0; r < 4; ++r) {
                int row = row0 + r;
                if (row < M) {
                    float o = acc[mt][nt][r] + bv;
                    if (jb.relu) o = fmaxf(o, 0.f);
                    if (jb.C)   jb.C[(size_t)row * 256 + col] = o;
                    if (jb.Cbf) jb.Cbf[(size_t)row * 256 + col] = f2bf(o);
                }
            }
        }
    }
}

// ---------------- prep1: makeBT + fill_weff + count ----------------
struct Prep1 { BTBatch bt; const float* Wsrc; const float* Wdst; const float* asrc;
               const float* adst; float* weff; EI8 ei; int* cnt; };

__global__ __launch_bounds__(256) void prep1_k(Prep1 a)
{
    int bx = blockIdx.x;
    if (bx < 4352) {
        BTJob jb = a.bt.j[bx >> 8];
        int idx = (bx & 255) * 256 + threadIdx.x;
        if (idx >= (jb.K << 8)) return;
        int n = idx >> jb.kshift;
        int k = idx & (jb.K - 1);
        float w = jb.W[(size_t)k * 256 + n];
        unsigned short h = f2bf(w);
        jb.hi[idx] = h;
        jb.lo[idx] = f2bf(w - bf2f(h));
    } else if (bx < 4672) {
        int idx = (bx - 4352) * 256 + threadIdx.x;
        if (idx >= 81920) return;
        int col = idx & 31;
        int k   = (idx >> 5) & 255;
        int lnt = idx >> 13;
        int nt  = lnt % 5;
        int l   = lnt / 5;
        bool is_src; int t, h;
        if (nt == 0) {
            if (col < 16) { is_src = true;  t = (col >> 2) * 2;            h = col & 3; }
            else          { is_src = false; t = ((col - 16) >> 2) * 2 + 1; h = col & 3; }
        } else {
            if (col < 4)      { is_src = true;  t = 2 * nt - 1; h = col; }
            else if (col < 8) { is_src = false; t = 2 * nt - 2; h = col - 4; }
            else { a.weff[idx] = 0.f; return; }
        }
        const float* W = (is_src ? a.Wsrc : a.Wdst) + ((size_t)((l * 8 + t) * 256 + k)) * 256 + h * 64;
        const float* av = (is_src ? a.asrc : a.adst) + ((size_t)((l * 8 + t) * 4 + h)) * 64;
        float val = 0.f;
        for (int c = 0; c < 64; c++) val += W[c] * av[c];
        a.weff[idx] = val;
    } else {
        int g = (bx - 4672) * 256 + threadIdx.x;
        if (g >= 8 * E_N) return;
        int t = g / E_N;
        int i = g - t * E_N;
        int d = a.ei.p[t][E_N + i];
        atomicAdd(&a.cnt[c_tbase[t] + d], 1);
    }
}

// ---------------- prep2: fillEff + scanA ----------------
__global__ __launch_bounds__(256) void prep2_k(const float* __restrict__ Wp_ts,
                                               const float* __restrict__ bp_ts,
                                               const float* __restrict__ Wp_c,
                                               const float* __restrict__ bp_c,
                                               const float* __restrict__ weff,
                                               float* __restrict__ effT, float* __restrict__ biasT,
                                               float* __restrict__ effC, float* __restrict__ biasC,
                                               const int* __restrict__ cnt,
                                               int* __restrict__ rowptr, int* __restrict__ bsum)
{
    if (blockIdx.x < 25) {
        int idx = blockIdx.x * 256 + threadIdx.x;
        if (idx < 2048) {
            int kk = idx >> 5, j = idx & 31;
            float s = 0.f;
            for (int k = 0; k < 256; k++) s += Wp_ts[kk * 256 + k] * weff[k * 32 + j];
            effT[idx] = s;
        } else if (idx < 2080) {
            int j = idx - 2048;
            float s = 0.f;
            for (int k = 0; k < 256; k++) s += bp_ts[k] * weff[k * 32 + j];
            biasT[j] = s;
        } else if (idx < 2080 + 4 * 1032) {
            int r = idx - 2080;
            int q = r / 1032; r -= q * 1032;
            const float* wq = weff + (q + 1) * 8192;
            if (r < 1024) {
                int kk = r >> 3, j = r & 7;
                float s = 0.f;
                for (int k = 0; k < 256; k++) s += Wp_c[(size_t)q * 32768 + kk * 256 + k] * wq[k * 32 + j];
                effC[(q * 128 + kk) * 8 + j] = s;
            } else {
                int j = r - 1024;
                float s = 0.f;
                for (int k = 0; k < 256; k++) s += bp_c[q * 256 + k] * wq[k * 32 + j];
                biasC[q * 8 + j] = s;
            }
        }
    } else {
        __shared__ int sd[256];
        int b = blockIdx.x - 25, t = threadIdx.x;
        int base = b * 1024 + t * 4;
        int v0 = 0, v1 = 0, v2 = 0, v3 = 0;
        if (base + 0 < NDST) v0 = cnt[base + 0];
        if (base + 1 < NDST) v1 = cnt[base + 1];
        if (base + 2 < NDST) v2 = cnt[base + 2];
        if (base + 3 < NDST) v3 = cnt[base + 3];
        int s = v0 + v1 + v2 + v3;
        sd[t] = s;
        __syncthreads();
        for (int off = 1; off < 256; off <<= 1) {
            int x = 0;
            if (t >= off) x = sd[t - off];
            __syncthreads();
            if (t >= off) sd[t] += x;
            __syncthreads();
        }
        int run = sd[t] - s;
        if (t == 255) bsum[b] = sd[255];
        if (base + 0 < NDST) rowptr[base + 0] = run;          run += v0;
        if (base + 1 < NDST) rowptr[base + 1] = run;          run += v1;
        if (base + 2 < NDST) rowptr[base + 2] = run;          run += v2;
        if (base + 3 < NDST) rowptr[base + 3] = run;
    }
}

__global__ __launch_bounds__(256) void scanB(int* __restrict__ bsum, int nb)
{
    __shared__ int sd[256];
    int t = threadIdx.x;
    int v = (t < nb) ? bsum[t] : 0;
    sd[t] = v;
    __syncthreads();
    for (int off = 1; off < 256; off <<= 1) {
        int x = 0;
        if (t >= off) x = sd[t - off];
        __syncthreads();
        if (t >= off) sd[t] += x;
        __syncthreads();
    }
    if (t < nb) bsum[t] = sd[t] - v;
}

// ---------------- prep3: scanC + attnprojA + attnprojC1 ----------------
struct Prep3 { int* rowptr; const int* bsum; int* cursor;
               const float* ts_x; const float* effT; const float* biasT; float* attnT;
               const float* e0; const float* e1; const float* e2; const float* e3;
               const float* effC; const float* biasC; float* attnC; };

__global__ __launch_bounds__(256) void prep3_k(Prep3 a)
{
    int bx = blockIdx.x;
    if (bx < 229) {
        int t = threadIdx.x;
        int off = a.bsum[bx];
        int base = bx * 1024 + t * 4;
#pragma unroll
        for (int j = 0; j < 4; j++) {
            int i = base + j;
            if (i < NDST) {
                int r = a.rowptr[i] + off;
                a.rowptr[i] = r;
                a.cursor[i] = r;
            }
        }
        if (bx == 0 && t == 0) a.rowptr[NDST] = 8 * E_N;
    } else if (bx < 425) {
        int n = (bx - 229) * 256 + threadIdx.x;
        if (n >= 50000) return;
        float acc[32];
#pragma unroll
        for (int j = 0; j < 32; j++) acc[j] = a.biasT[j];
        const float* xr = a.ts_x + (size_t)n * 64;
        for (int k = 0; k < 64; k += 4) {
            float4 xv = *(const float4*)(xr + k);
#pragma unroll
            for (int j = 0; j < 32; j++)
                acc[j] += xv.x * a.effT[(k + 0) * 32 + j] + xv.y * a.effT[(k + 1) * 32 + j]
                        + xv.z * a.effT[(k + 2) * 32 + j] + xv.w * a.effT[(k + 3) * 32 + j];
        }
#pragma unroll
        for (int j = 0; j < 32; j++) a.attnT[(size_t)n * 32 + j] = acc[j];
    } else {
        int m = (bx - 425) * 256 + threadIdx.x;
        if (m >= 34000) return;
        int q, loc;
        if (m < 1000)       { q = 0; loc = m; }
        else if (m < 21000) { q = 1; loc = m - 1000; }
        else if (m < 26000) { q = 2; loc = m - 21000; }
        else                { q = 3; loc = m - 26000; }
        const float* er = (q == 0 ? a.e0 : q == 1 ? a.e1 : q == 2 ? a.e2 : a.e3) + (size_t)loc * 128;
        const float* W = a.effC + q * 1024;
        float acc[8];
#pragma unroll
        for (int j = 0; j < 8; j++) acc[j] = a.biasC[q * 8 + j];
        for (int k = 0; k < 128; k += 4) {
            float4 xv = *(const float4*)(er + k);
#pragma unroll
            for (int j = 0; j < 8; j++)
                acc[j] += xv.x * W[(k + 0) * 8 + j] + xv.y * W[(k + 1) * 8 + j]
                        + xv.z * W[(k + 2) * 8 + j] + xv.w * W[(k + 3) * 8 + j];
        }
#pragma unroll
        for (int j = 0; j < 8; j++) a.attnC[(size_t)m * 8 + j] = acc[j];
    }
}

// ---------------- projplace: proj GEMMs + CSR place + L1 logit bake (independent) ----
struct ProjPlace { MBatch mb; EI8 ei; int* cursor; int* ssrc; int* sdst; float* exf;
                   const float* attnT; const float* attnC; };

__global__ __launch_bounds__(256, 2) void projplace_k(ProjPlace a)
{
    if (blockIdx.x < 3920) {
        gemm_body(a.mb.j[blockIdx.x / 784], blockIdx.x % 784);
    } else {
        int g = (blockIdx.x - 3920) * 256 + threadIdx.x;
        if (g >= 8 * E_N) return;
        int t = g / E_N;
        int i = g - t * E_N;
        int d = a.ei.p[t][E_N + i];
        int s = a.ei.p[t][i];
        int pos = atomicAdd(&a.cursor[c_tbase[t] + d], 1);
        a.ssrc[pos] = s;
        a.sdst[pos] = d;
        int q = t >> 1;
        float4 ex;
        if ((t & 1) == 0) {   // ts -> compact
            int w = c_co4[q] + d;
            int soff = 4 * q;
            ex.x = __expf(lrelu(a.attnT[(size_t)s * 32 + soff + 0] + a.attnC[(size_t)w * 8 + 4]));
            ex.y = __expf(lrelu(a.attnT[(size_t)s * 32 + soff + 1] + a.attnC[(size_t)w * 8 + 5]));
            ex.z = __expf(lrelu(a.attnT[(size_t)s * 32 + soff + 2] + a.attnC[(size_t)w * 8 + 6]));
            ex.w = __expf(lrelu(a.attnT[(size_t)s * 32 + soff + 3] + a.attnC[(size_t)w * 8 + 7]));
        } else {              // compact -> ts
            int m = c_co4[q] + s;
            int doff = 16 + 4 * q;
            ex.x = __expf(lrelu(a.attnC[(size_t)m * 8 + 0] + a.attnT[(size_t)d * 32 + doff + 0]));
            ex.y = __expf(lrelu(a.attnC[(size_t)m * 8 + 1] + a.attnT[(size_t)d * 32 + doff + 1]));
            ex.z = __expf(lrelu(a.attnC[(size_t)m * 8 + 2] + a.attnT[(size_t)d * 32 + doff + 2]));
            ex.w = __expf(lrelu(a.attnC[(size_t)m * 8 + 3] + a.attnT[(size_t)d * 32 + doff + 3]));
        }
        *(float4*)(a.exf + (size_t)pos * 4) = ex;
    }
}

// ---------------- agg core (exf-based, sequential-q, unroll-2) ----------------
__device__ __forceinline__ float4 agg_core(const float* __restrict__ exf,
                                           const unsigned short* __restrict__ hscbf,
                                           const int* __restrict__ rowptr,
                                           const int* __restrict__ ssrc,
                                           const float* __restrict__ bconv_l,
                                           int d, int h, int ch)
{
    const int co4[4] = {0, 1000, 21000, 26000};
    const int tb4[4] = {1000, 71000, 126000, 184000};
    const int bo4[4] = {256, 768, 1280, 1792};
    float ax = 0.f, ay = 0.f, az = 0.f, aw = 0.f;
#pragma unroll
    for (int q = 0; q < 4; q++) {
        int r0 = rowptr[tb4[q] + d], r1 = rowptr[tb4[q] + d + 1];
        float den = 0.f, sx = 0.f, sy = 0.f, sz = 0.f, sw = 0.f;
        int e = r0;
        for (; e + 2 <= r1; e += 2) {
            int sA = ssrc[e], sB = ssrc[e + 1];
            float xA = exf[(size_t)e * 4 + h];
            float xB = exf[(size_t)(e + 1) * 4 + h];
            ushort4 rA = *(const ushort4*)(hscbf + (size_t)(co4[q] + sA) * 256 + ch);
            ushort4 rB = *(const ushort4*)(hscbf + (size_t)(co4[q] + sB) * 256 + ch);
            den += xA + xB;
            sx += xA * bf2f(rA.x) + xB * bf2f(rB.x);
            sy += xA * bf2f(rA.y) + xB * bf2f(rB.y);
            sz += xA * bf2f(rA.z) + xB * bf2f(rB.z);
            sw += xA * bf2f(rA.w) + xB * bf2f(rB.w);
        }
        if (e < r1) {
            int s = ssrc[e];
            float x = exf[(size_t)e * 4 + h];
            den += x;
            ushort4 hv = *(const ushort4*)(hscbf + (size_t)(co4[q] + s) * 256 + ch);
            sx += x * bf2f(hv.x); sy += x * bf2f(hv.y);
            sz += x * bf2f(hv.z); sw += x * bf2f(hv.w);
        }
        const float* b = bconv_l + bo4[q] + ch;
        float inv = 1.f / (den + 1e-16f);
        ax += b[0] + sx * inv; ay += b[1] + sy * inv;
        az += b[2] + sz * inv; aw += b[3] + sw * inv;
    }
    float4 o;
    o.x = fmaxf(ax, 0.f); o.y = fmaxf(ay, 0.f);
    o.z = fmaxf(az, 0.f); o.w = fmaxf(aw, 0.f);
    return o;
}

// ---------------- l1a: GEMM jobs (x0 compact -> hscbf) + aggx (independent) ----------
struct L1A { MBatch mb; const float* exf; const unsigned short* xtsbf;
             const int* rowptr; const int* ssrc; float* aggx; };

__global__ __launch_bounds__(256, 2) void l1a_k(L1A a)
{
    if (blockIdx.x < 1280) {
        gemm_body(a.mb.j[blockIdx.x / 320], blockIdx.x % 320);
        return;
    }
    int w = (blockIdx.x - 1280) * 4 + (threadIdx.x >> 6);   // 0..33999
    int lane = threadIdx.x & 63;
    int h = lane >> 4;
    int ch = (h << 6) | ((lane & 15) << 2);
    int q, dloc;
    if (w < 1000)       { q = 0; dloc = w; }
    else if (w < 21000) { q = 1; dloc = w - 1000; }
    else if (w < 26000) { q = 2; dloc = w - 21000; }
    else                { q = 3; dloc = w - 26000; }
    const int csr4[4] = {0, 51000, 121000, 176000};
    int r0 = a.rowptr[csr4[q] + dloc], r1 = a.rowptr[csr4[q] + dloc + 1];
    float den = 0.f, sx = 0.f, sy = 0.f, sz = 0.f, sw = 0.f;
    int e = r0;
    for (; e + 4 <= r1; e += 4) {
        int sA = a.ssrc[e], sB = a.ssrc[e + 1], sC = a.ssrc[e + 2], sD = a.ssrc[e + 3];
        float xA = a.exf[(size_t)e * 4 + h];
        float xB = a.exf[(size_t)(e + 1) * 4 + h];
        float xC = a.exf[(size_t)(e + 2) * 4 + h];
        float xD = a.exf[(size_t)(e + 3) * 4 + h];
        ushort4 rA = *(const ushort4*)(a.xtsbf + (size_t)sA * 256 + ch);
        ushort4 rB = *(const ushort4*)(a.xtsbf + (size_t)sB * 256 + ch);
        ushort4 rC = *(const ushort4*)(a.xtsbf + (size_t)sC * 256 + ch);
        ushort4 rD = *(const ushort4*)(a.xtsbf + (size_t)sD * 256 + ch);
        den += (xA + xB) + (xC + xD);
        sx += xA * bf2f(rA.x) + xB * bf2f(rB.x) + xC * bf2f(rC.x) + xD * bf2f(rD.x);
        sy += xA * bf2f(rA.y) + xB * bf2f(rB.y) + xC * bf2f(rC.y) + xD * bf2f(rD.y);
        sz += xA * bf2f(rA.z) + xB * bf2f(rB.z) + xC * bf2f(rC.z) + xD * bf2f(rD.z);
        sw += xA * bf2f(rA.w) + xB * bf2f(rB.w) + xC * bf2f(rC.w) + xD * bf2f(rD.w);
    }
    for (; e < r1; e++) {
        int s = a.ssrc[e];
        float x = a.exf[(size_t)e * 4 + h];
        den += x;
        ushort4 rv = *(const ushort4*)(a.xtsbf + (size_t)s * 256 + ch);
        sx += x * bf2f(rv.x); sy += x * bf2f(rv.y);
        sz += x * bf2f(rv.z); sw += x * bf2f(rv.w);
    }
    float inv = 1.f / (den + 1e-16f);
    float4 o; o.x = sx * inv; o.y = sy * inv; o.z = sz * inv; o.w = sw * inv;
    *(float4*)(a.aggx + (size_t)w * 256 + ch) = o;
}

// ---------------- l1b: GEMM jobs (aggx -> x1 compact) + L1 ts-agg w/ fold ------------
struct L1B { MBatch mb; float* attnT; const float* exf; const unsigned short* hscbf;
             const int* rowptr; const int* ssrc; const float* bconv_l; const float* weff2; };

__global__ __launch_bounds__(256, 2) void l1b_k(L1B a)
{
    if (blockIdx.x < 1280) {
        gemm_body(a.mb.j[blockIdx.x / 320], blockIdx.x % 320);
        return;
    }
    int bx = blockIdx.x - 1280;                 // 0..12499
    int wv = threadIdx.x >> 6;
    int d = bx * 4 + wv;
    int lane = threadIdx.x & 63;
    int h = lane >> 4;
    int ch = (h << 6) | ((lane & 15) << 2);
    float4 o = agg_core(a.exf, a.hscbf, a.rowptr, a.ssrc, a.bconv_l, d, h, ch);
    __shared__ float rowbuf[4][256];
    rowbuf[wv][ch + 0] = o.x; rowbuf[wv][ch + 1] = o.y;
    rowbuf[wv][ch + 2] = o.z; rowbuf[wv][ch + 3] = o.w;
    __syncthreads();
    int j = lane & 15, seg = lane >> 4;
    const float* rb = rowbuf[wv] + seg * 64;
    const float* w2 = a.weff2 + (seg * 64) * 32 + 16 + j;
    float s = 0.f;
#pragma unroll 8
    for (int c = 0; c < 64; c++) s += rb[c] * w2[c * 32];
    s += __shfl_xor(s, 16);
    s += __shfl_xor(s, 32);
    if (lane < 16) a.attnT[(size_t)d * 32 + 16 + lane] = s;
}

// ---------------- l2a: L2 GEMM (x1 -> hscbf) + attnprojC2 (x1 -> attnC) --------------
struct L2A { MBatch mb; const float* x1; const float* weff2; float* attnC; };

__global__ __launch_bounds__(256, 2) void l2a_k(L2A a)
{
    if (blockIdx.x < 1280) {
        gemm_body(a.mb.j[blockIdx.x / 320], blockIdx.x % 320);
        return;
    }
    int m = (blockIdx.x - 1280) * 256 + threadIdx.x;
    if (m >= 34000) return;
    int n = 50000 + m;
    int nt = (n < 51000) ? 1 : (n < 71000) ? 2 : (n < 76000) ? 3 : 4;
    const float* xrow = a.x1 + (size_t)n * 256;
    const float* W = a.weff2 + nt * 8192;
    float acc[8];
#pragma unroll
    for (int j = 0; j < 8; j++) acc[j] = 0.f;
    for (int k = 0; k < 256; k += 4) {
        const float4 xv = *(const float4*)(xrow + k);
#pragma unroll
        for (int j = 0; j < 8; j++)
            acc[j] += xv.x * W[(k + 0) * 32 + j] + xv.y * W[(k + 1) * 32 + j]
                    + xv.z * W[(k + 2) * 32 + j] + xv.w * W[(k + 3) * 32 + j];
    }
#pragma unroll
    for (int j = 0; j < 8; j++) a.attnC[(size_t)m * 8 + j] = acc[j];
}

// ---------------- bake_k: L2 logits for odd-type slots ----------------
__global__ __launch_bounds__(256) void bake_k(const int* __restrict__ ssrc,
                                              const int* __restrict__ sdst,
                                              const float* __restrict__ attnC,
                                              const float* __restrict__ attnT,
                                              float* __restrict__ exf)
{
    int i = blockIdx.x * 256 + threadIdx.x;
    if (i >= 400000) return;
    int tq = i / E_N;
    int i2 = i - tq * E_N;
    int e = (2 * tq + 1) * E_N + i2;
    int s = ssrc[e], d = sdst[e];
    int m = c_co4[tq] + s;
    int doff = 16 + 4 * tq;
    float4 ex;
    ex.x = __expf(lrelu(attnC[(size_t)m * 8 + 0] + attnT[(size_t)d * 32 + doff + 0]));
    ex.y = __expf(lrelu(attnC[(size_t)m * 8 + 1] + attnT[(size_t)d * 32 + doff + 1]));
    ex.z = __expf(lrelu(attnC[(size_t)m * 8 + 2] + attnT[(size_t)d * 32 + doff + 2]));
    ex.w = __expf(lrelu(attnC[(size_t)m * 8 + 3] + attnT[(size_t)d * 32 + doff + 3]));
    *(float4*)(exf + (size_t)e * 4) = ex;
}

// ---------------- pool: L2 aggregation + per-block partial ----------------
__global__ __launch_bounds__(256) void pool_k(const float* __restrict__ exf,
                                              const unsigned short* __restrict__ hscbf,
                                              const int* __restrict__ rowptr,
                                              const int* __restrict__ ssrc,
                                              const float* __restrict__ bconv_l,
                                              float* __restrict__ part)
{
    int d = blockIdx.x * 4 + (threadIdx.x >> 6);
    int lane = threadIdx.x & 63;
    int h = lane >> 4;
    int ch = (h << 6) | ((lane & 15) << 2);
    float4 o = agg_core(exf, hscbf, rowptr, ssrc, bconv_l, d, h, ch);
    __shared__ float4 red4[256];
    red4[threadIdx.x] = o;
    __syncthreads();
    if (threadIdx.x < 64) {
        float4 a = red4[threadIdx.x], b = red4[threadIdx.x + 64];
        float4 c = red4[threadIdx.x + 128], dd = red4[threadIdx.x + 192];
        float4 s;
        s.x = (a.x + b.x) + (c.x + dd.x);
        s.y = (a.y + b.y) + (c.y + dd.y);
        s.z = (a.z + b.z) + (c.z + dd.z);
        s.w = (a.w + b.w) + (c.w + dd.w);
        int cch = ((threadIdx.x >> 4) << 6) | ((threadIdx.x & 15) << 2);
        *(float4*)(part + (size_t)blockIdx.x * 256 + cch) = s;
    }
}

__global__ __launch_bounds__(256) void colsum_part(const float* __restrict__ part,
                                                   float* __restrict__ gsum)
{
    int c = threadIdx.x;
    float s = 0.f;
    for (int r = blockIdx.x; r < 12500; r += gridDim.x) s += part[(size_t)r * 256 + c];
    atomAddF(gsum + c, s);
}

__global__ __launch_bounds__(128) void head_k(const float* __restrict__ gsum,
                                              const float* __restrict__ Wc1,
                                              const float* __restrict__ bc1,
                                              const float* __restrict__ Wc2,
                                              const float* __restrict__ bc2,
                                              float* __restrict__ out)
{
    __shared__ float g[256];
    __shared__ float red[128];
    int t = threadIdx.x;
    g[t] = gsum[t] * (1.f / 50000.f);
    g[t + 128] = gsum[t + 128] * (1.f / 50000.f);
    __syncthreads();
    float acc = bc1[t];
    for (int k = 0; k < 256; k++) acc += g[k] * Wc1[k * 128 + t];
    red[t] = fmaxf(acc, 0.f) * Wc2[t];
    __syncthreads();
    for (int sft = 64; sft > 0; sft >>= 1) {
        if (t < sft) red[t] += red[t + sft];
        __syncthreads();
    }
    if (t == 0) out[0] = red[0] + bc2[0];
}

extern "C" void kernel_launch(void* const* d_in, const int* in_sizes, int n_in,
                              void* d_out, int out_size, void* d_ws, size_t ws_size,
                              hipStream_t stream)
{
    const float* ts_x   = (const float*)d_in[0];
    const float* emb[4] = {(const float*)d_in[1], (const float*)d_in[2],
                           (const float*)d_in[3], (const float*)d_in[4]};
    const float* Wp_ts  = (const float*)d_in[5];
    const float* bp_ts  = (const float*)d_in[6];
    const float* Wp_c   = (const float*)d_in[7];
    const float* bp_c   = (const float*)d_in[8];
    const float* Wsrc   = (const float*)d_in[9];
    const float* Wdst   = (const float*)d_in[10];
    const float* asrc   = (const float*)d_in[11];
    const float* adst   = (const float*)d_in[12];
    const float* bconv  = (const float*)d_in[13];
    const float* Wc1    = (const float*)d_in[14];
    const float* bc1    = (const float*)d_in[15];
    const float* Wc2    = (const float*)d_in[16];
    const float* bc2    = (const float*)d_in[17];
    EI8 ei;
    for (int t = 0; t < 8; t++) ei.p[t] = (const int*)d_in[18 + t];

    // workspace layout (float units) -- identical footprint to round 10 (passed)
    float* x0    = (float*)d_ws;            // 21,504,000 (ts region reused: exf/sdst/part)
    float* x1    = x0    + 21504000;        // 21,504,000 (ts region = aggx; compact = L2 input)
    float* attnT = x1    + 21504000;        // 1,600,000
    float* attnC = attnT + 1600000;         // 272,000 (L1, reused for L2)
    float* weff  = attnC + 272000;          // 81,920
    float* gsum  = weff  + 81920;           // 256
    float* effT  = gsum  + 256;             // 2,048
    float* biasT = effT  + 2048;            // 32
    float* effC  = biasT + 32;              // 4,096
    float* biasC = effC  + 4096;            // 32
    int* rowptr  = (int*)(biasC + 32);      // 234,004
    int* bsum    = rowptr + 234004;         // 256
    int* ssrc    = bsum + 256;              // 800,000
    unsigned short* xtsbf = (unsigned short*)(ssrc + 800000);   // 12,800,000 us
    unsigned short* hscbf = xtsbf + 12800000;                   //  8,704,000 us
    unsigned short* btp   = hscbf + 8704000;                    //  1,867,776 us
    int* cursor  = (int*)hscbf;             // alias: CSR build finishes before hscbf used
    float* aggx  = x1;                      // alias x1 ts region (rows 0..33999)
    // x0 ts region (12.8M floats) never holds x -> carve exf/sdst/part out of it
    float* exf   = x0;                      // 3,200,000
    int* sdst    = (int*)(x0 + 3200000);    // 800,000
    float* part  = x0 + 4200000;            // 3,200,000

    unsigned short* bt_ts_h = btp;
    unsigned short* bt_ts_l = bt_ts_h + 16384;
    unsigned short* bt_c_h[4], *bt_c_l[4];
    {
        unsigned short* p = bt_ts_l + 16384;
        for (int q = 0; q < 4; q++) { bt_c_h[q] = p; p += 32768; bt_c_l[q] = p; p += 32768; }
    }
    unsigned short* bt_w = bt_ts_l + 16384 + 8 * 32768;
    auto wpan_h = [&](int l, int t) { return bt_w + (size_t)((l == 0 ? t : 8 + t / 2) * 2) * 65536; };
    auto wpan_l = [&](int l, int t) { return wpan_h(l, t) + 65536; };

    static const int Nd4[4]    = {1000, 20000, 5000, 8000};
    static const int co4[4]    = {0, 1000, 21000, 26000};
    static const int dbase4[4] = {50000, 51000, 71000, 76000};
    static const int tsrc[4]   = {1, 3, 5, 7};
    static const int tdst[4]   = {0, 2, 4, 6};

    hipMemsetAsync(cursor, 0, NDST * sizeof(int), stream);

    // ---- prep1: makeBT + fill_weff + count ----
    {
        Prep1 a = {};
        int zi = 0;
        a.bt.j[zi++] = {Wp_ts, bt_ts_h, bt_ts_l, 64, 6};
        for (int q = 0; q < 4; q++)
            a.bt.j[zi++] = {Wp_c + q * 32768, bt_c_h[q], bt_c_l[q], 128, 7};
        for (int t = 0; t < 8; t++)
            a.bt.j[zi++] = {Wsrc + (size_t)(0 * 8 + t) * 65536, wpan_h(0, t), wpan_l(0, t), 256, 8};
        for (int t = 1; t < 8; t += 2)
            a.bt.j[zi++] = {Wsrc + (size_t)(1 * 8 + t) * 65536, wpan_h(1, t), wpan_l(1, t), 256, 8};
        a.Wsrc = Wsrc; a.Wdst = Wdst; a.asrc = asrc; a.adst = adst;
        a.weff = weff; a.ei = ei; a.cnt = cursor;
        prep1_k<<<7797, 256, 0, stream>>>(a);
    }

    // ---- prep2: fillEff + scanA ----
    prep2_k<<<254, 256, 0, stream>>>(Wp_ts, bp_ts, Wp_c, bp_c, weff,
                                     effT, biasT, effC, biasC, cursor, rowptr, bsum);
    scanB<<<1, 256, 0, stream>>>(bsum, 229);

    // ---- prep3: scanC + attnprojA + attnprojC1 ----
    {
        Prep3 a = {rowptr, bsum, cursor, ts_x, effT, biasT, attnT,
                   emb[0], emb[1], emb[2], emb[3], effC, biasC, attnC};
        prep3_k<<<558, 256, 0, stream>>>(a);
    }

    // ---- projplace: input projections + CSR place + L1 logit bake ----
    {
        ProjPlace a = {};
        a.mb.j[0] = {ts_x, bt_ts_h, bt_ts_l, nullptr, xtsbf, bp_ts, 50000, 64, 0};
        for (int q = 0; q < 4; q++)
            a.mb.j[1 + q] = {emb[q], bt_c_h[q], bt_c_l[q], x0 + (size_t)dbase4[q] * 256,
                             nullptr, bp_c + q * 256, Nd4[q], 128, 0};
        a.ei = ei; a.cursor = cursor; a.ssrc = ssrc; a.sdst = sdst; a.exf = exf;
        a.attnT = attnT; a.attnC = attnC;
        projplace_k<<<7045, 256, 0, stream>>>(a);
    }

    // ---- l1a: GEMM (x0 compact -> hscbf) + aggx  [independent] ----
    {
        L1A a = {};
        for (int q = 0; q < 4; q++)
            a.mb.j[q] = {x0 + (size_t)dbase4[q] * 256, wpan_h(0, tsrc[q]), wpan_l(0, tsrc[q]),
                         nullptr, hscbf + (size_t)co4[q] * 256, nullptr, Nd4[q], 256, 0};
        a.exf = exf; a.xtsbf = xtsbf; a.rowptr = rowptr; a.ssrc = ssrc; a.aggx = aggx;
        l1a_k<<<9780, 256, 0, stream>>>(a);
    }

    // ---- l1b: GEMM (aggx -> x1 compact) + L1 ts-agg w/ attnT_L2 fold  [independent] --
    {
        L1B a = {};
        for (int q = 0; q < 4; q++)
            a.mb.j[q] = {aggx + (size_t)co4[q] * 256, wpan_h(0, tdst[q]), wpan_l(0, tdst[q]),
                         x1 + (size_t)dbase4[q] * 256, nullptr, bconv + tdst[q] * 256, Nd4[q], 256, 1};
        a.attnT = attnT; a.exf = exf; a.hscbf = hscbf; a.rowptr = rowptr; a.ssrc = ssrc;
        a.bconv_l = bconv; a.weff2 = weff + 40960;
        l1b_k<<<13780, 256, 0, stream>>>(a);
    }

    // ---- l2a: L2 GEMM (x1 -> hscbf) + attnprojC2 (x1 -> attnC)  [independent] ----
    {
        L2A a = {};
        for (int q = 0; q < 4; q++)
            a.mb.j[q] = {x1 + (size_t)dbase4[q] * 256, wpan_h(1, tsrc[q]), wpan_l(1, tsrc[q]),
                         nullptr, hscbf + (size_t)co4[q] * 256, nullptr, Nd4[q], 256, 0};
        a.x1 = x1; a.weff2 = weff + 40960; a.attnC = attnC;
        l2a_k<<<1413, 256, 0, stream>>>(a);
    }

    // ---- bake L2 logits, then pool + reduce + head ----
    bake_k<<<1563, 256, 0, stream>>>(ssrc, sdst, attnC, attnT, exf);
    hipMemsetAsync(gsum, 0, 256 * sizeof(float), stream);
    pool_k<<<12500, 256, 0, stream>>>(exf, hscbf, rowptr, ssrc, bconv + 2048, part);
    colsum_part<<<256, 256, 0, stream>>>(part, gsum);
    head_k<<<1, 128, 0, stream>>>(gsum, Wc1, bc1, Wc2, bc2, (float*)d_out);
}

// Round 13
// 644.800 us; speedup vs baseline: 1.1144x; 1.1144x over previous
//
#include <hip/hip_runtime.h>

#define E_N 100000
#define NDST 234000   // concatenated per-type dst index space

typedef __attribute__((ext_vector_type(8))) short bfrag8;
typedef __attribute__((ext_vector_type(4))) float accf4;

__device__ __forceinline__ void atomAddF(float* p, float v) { unsafeAtomicAdd(p, v); }
__device__ __forceinline__ float lrelu(float v) { return v >= 0.f ? v : 0.2f * v; }

__device__ __forceinline__ unsigned short f2bf(float f) {
    unsigned u = __float_as_uint(f);
    return (unsigned short)((u + 0x7FFFu + ((u >> 16) & 1u)) >> 16);
}
__device__ __forceinline__ float bf2f(unsigned short h) {
    return __uint_as_float(((unsigned)h) << 16);
}

__constant__ int c_tbase[8] = {0, 1000, 51000, 71000, 121000, 126000, 176000, 184000};
__constant__ int c_co4[4]   = {0, 1000, 21000, 26000};

struct EI8 { const int* p[8]; };

struct BTJob { const float* W; unsigned short* hi; unsigned short* lo; int K; int kshift; };
struct BTBatch { BTJob j[17]; };

struct MJob { const float* A; const unsigned short* BThi; const unsigned short* BTlo;
              float* C; unsigned short* Cbf; const float* bias; int M; int K; int relu; };
struct MBatch { MJob j[8]; };

// ---------------- MFMA split-bf16 GEMM body (128x128 tile, paired-half decode) -------
__device__ __forceinline__ void gemm_body(const MJob jb, int bx)
{
    const int rowblk = (bx >> 4) * 8 + (bx & 7);
    const int half = (bx >> 3) & 1;
    const int bm = rowblk * 128;
    if (bm >= jb.M) return;
    const int bn = half * 128;
    const int M = jb.M, K = jb.K;

    __shared__ unsigned short Ah[128 * 40];
    __shared__ unsigned short Al[128 * 40];
    __shared__ unsigned short B1[128 * 40];
    __shared__ unsigned short B2[128 * 40];

    const int tid  = threadIdx.x;
    const int wv   = tid >> 6;
    const int lane = tid & 63;
    const int qr = wv >> 1, qc = wv & 1;
    const int lm = lane & 15;
    const int lq = lane >> 4;

    accf4 acc[4][4] = {};

    for (int k0 = 0; k0 < K; k0 += 32) {
#pragma unroll
        for (int it = 0; it < 4; ++it) {
            int slot = it * 256 + tid;
            int m  = slot >> 3;
            int kq = (slot & 7) << 2;
            float4 v = make_float4(0.f, 0.f, 0.f, 0.f);
            if (bm + m < M) v = *(const float4*)(jb.A + (size_t)(bm + m) * K + k0 + kq);
            int o = m * 40 + kq;
            unsigned short h0 = f2bf(v.x), h1 = f2bf(v.y), h2 = f2bf(v.z), h3 = f2bf(v.w);
            Ah[o + 0] = h0; Ah[o + 1] = h1; Ah[o + 2] = h2; Ah[o + 3] = h3;
            Al[o + 0] = f2bf(v.x - bf2f(h0));
            Al[o + 1] = f2bf(v.y - bf2f(h1));
            Al[o + 2] = f2bf(v.z - bf2f(h2));
            Al[o + 3] = f2bf(v.w - bf2f(h3));
        }
#pragma unroll
        for (int it = 0; it < 2; ++it) {
            int slot = it * 256 + tid;
            int n  = slot >> 2;
            int kq = (slot & 3) << 3;
            size_t go = (size_t)(bn + n) * K + k0 + kq;
            *(uint4*)&B1[n * 40 + kq] = *(const uint4*)(jb.BThi + go);
            *(uint4*)&B2[n * 40 + kq] = *(const uint4*)(jb.BTlo + go);
        }
        __syncthreads();

        bfrag8 ah[4], al[4], b1[4], b2[4];
#pragma unroll
        for (int t = 0; t < 4; ++t) {
            int am  = qr * 64 + t * 16 + lm;
            int bnn = qc * 64 + t * 16 + lm;
            ah[t] = *(const bfrag8*)&Ah[am * 40 + lq * 8];
            al[t] = *(const bfrag8*)&Al[am * 40 + lq * 8];
            b1[t] = *(const bfrag8*)&B1[bnn * 40 + lq * 8];
            b2[t] = *(const bfrag8*)&B2[bnn * 40 + lq * 8];
        }
#pragma unroll
        for (int mt = 0; mt < 4; ++mt)
#pragma unroll
            for (int nt = 0; nt < 4; ++nt) {
                acc[mt][nt] = __builtin_amdgcn_mfma_f32_16x16x32_bf16(ah[mt], b1[nt], acc[mt][nt], 0, 0, 0);
                acc[mt][nt] = __builtin_amdgcn_mfma_f32_16x16x32_bf16(al[mt], b1[nt], acc[mt][nt], 0, 0, 0);
                acc[mt][nt] = __builtin_amdgcn_mfma_f32_16x16x32_bf16(ah[mt], b2[nt], acc[mt][nt], 0, 0, 0);
            }
        __syncthreads();
    }

#pragma unroll
    for (int nt = 0; nt < 4; ++nt) {
        int col = bn + qc * 64 + nt * 16 + lm;
        float bv = jb.bias ? jb.bias[col] : 0.f;
#pragma unroll
        for (int mt = 0; mt < 4; ++mt) {
            int row0 = bm + qr * 64 + mt * 16 + lq * 4;
#pragma unroll
            for (int r = 0; r < 4; ++r) {
                int row = row0 + r;
                if (row < M) {
                    float o = acc[mt][nt][r] + bv;
                    if (jb.relu) o = fmaxf(o, 0.f);
                    if (jb.C)   jb.C[(size_t)row * 256 + col] = o;
                    if (jb.Cbf) jb.Cbf[(size_t)row * 256 + col] = f2bf(o);
                }
            }
        }
    }
}

// GEMM-only multi-job launch: job = blockIdx.x / 320
__global__ __launch_bounds__(256, 2) void gemm_mb(MBatch b)
{
    gemm_body(b.j[blockIdx.x / 320], blockIdx.x % 320);
}

// ---------------- prep1: makeBT + fill_weff + count ----------------
struct Prep1 { BTBatch bt; const float* Wsrc; const float* Wdst; const float* asrc;
               const float* adst; float* weff; EI8 ei; int* cnt; };

__global__ __launch_bounds__(256) void prep1_k(Prep1 a)
{
    int bx = blockIdx.x;
    if (bx < 4352) {
        BTJob jb = a.bt.j[bx >> 8];
        int idx = (bx & 255) * 256 + threadIdx.x;
        if (idx >= (jb.K << 8)) return;
        int n = idx >> jb.kshift;
        int k = idx & (jb.K - 1);
        float w = jb.W[(size_t)k * 256 + n];
        unsigned short h = f2bf(w);
        jb.hi[idx] = h;
        jb.lo[idx] = f2bf(w - bf2f(h));
    } else if (bx < 4672) {
        int idx = (bx - 4352) * 256 + threadIdx.x;
        if (idx >= 81920) return;
        int col = idx & 31;
        int k   = (idx >> 5) & 255;
        int lnt = idx >> 13;
        int nt  = lnt % 5;
        int l   = lnt / 5;
        bool is_src; int t, h;
        if (nt == 0) {
            if (col < 16) { is_src = true;  t = (col >> 2) * 2;            h = col & 3; }
            else          { is_src = false; t = ((col - 16) >> 2) * 2 + 1; h = col & 3; }
        } else {
            if (col < 4)      { is_src = true;  t = 2 * nt - 1; h = col; }
            else if (col < 8) { is_src = false; t = 2 * nt - 2; h = col - 4; }
            else { a.weff[idx] = 0.f; return; }
        }
        const float* W = (is_src ? a.Wsrc : a.Wdst) + ((size_t)((l * 8 + t) * 256 + k)) * 256 + h * 64;
        const float* av = (is_src ? a.asrc : a.adst) + ((size_t)((l * 8 + t) * 4 + h)) * 64;
        float val = 0.f;
        for (int c = 0; c < 64; c++) val += W[c] * av[c];
        a.weff[idx] = val;
    } else {
        int g = (bx - 4672) * 256 + threadIdx.x;
        if (g >= 8 * E_N) return;
        int t = g / E_N;
        int i = g - t * E_N;
        int d = a.ei.p[t][E_N + i];
        atomicAdd(&a.cnt[c_tbase[t] + d], 1);
    }
}

// ---------------- prep2: fillEff + scanA ----------------
__global__ __launch_bounds__(256) void prep2_k(const float* __restrict__ Wp_ts,
                                               const float* __restrict__ bp_ts,
                                               const float* __restrict__ Wp_c,
                                               const float* __restrict__ bp_c,
                                               const float* __restrict__ weff,
                                               float* __restrict__ effT, float* __restrict__ biasT,
                                               float* __restrict__ effC, float* __restrict__ biasC,
                                               const int* __restrict__ cnt,
                                               int* __restrict__ rowptr, int* __restrict__ bsum)
{
    if (blockIdx.x < 25) {
        int idx = blockIdx.x * 256 + threadIdx.x;
        if (idx < 2048) {
            int kk = idx >> 5, j = idx & 31;
            float s = 0.f;
            for (int k = 0; k < 256; k++) s += Wp_ts[kk * 256 + k] * weff[k * 32 + j];
            effT[idx] = s;
        } else if (idx < 2080) {
            int j = idx - 2048;
            float s = 0.f;
            for (int k = 0; k < 256; k++) s += bp_ts[k] * weff[k * 32 + j];
            biasT[j] = s;
        } else if (idx < 2080 + 4 * 1032) {
            int r = idx - 2080;
            int q = r / 1032; r -= q * 1032;
            const float* wq = weff + (q + 1) * 8192;
            if (r < 1024) {
                int kk = r >> 3, j = r & 7;
                float s = 0.f;
                for (int k = 0; k < 256; k++) s += Wp_c[(size_t)q * 32768 + kk * 256 + k] * wq[k * 32 + j];
                effC[(q * 128 + kk) * 8 + j] = s;
            } else {
                int j = r - 1024;
                float s = 0.f;
                for (int k = 0; k < 256; k++) s += bp_c[q * 256 + k] * wq[k * 32 + j];
                biasC[q * 8 + j] = s;
            }
        }
    } else {
        __shared__ int sd[256];
        int b = blockIdx.x - 25, t = threadIdx.x;
        int base = b * 1024 + t * 4;
        int v0 = 0, v1 = 0, v2 = 0, v3 = 0;
        if (base + 0 < NDST) v0 = cnt[base + 0];
        if (base + 1 < NDST) v1 = cnt[base + 1];
        if (base + 2 < NDST) v2 = cnt[base + 2];
        if (base + 3 < NDST) v3 = cnt[base + 3];
        int s = v0 + v1 + v2 + v3;
        sd[t] = s;
        __syncthreads();
        for (int off = 1; off < 256; off <<= 1) {
            int x = 0;
            if (t >= off) x = sd[t - off];
            __syncthreads();
            if (t >= off) sd[t] += x;
            __syncthreads();
        }
        int run = sd[t] - s;
        if (t == 255) bsum[b] = sd[255];
        if (base + 0 < NDST) rowptr[base + 0] = run;          run += v0;
        if (base + 1 < NDST) rowptr[base + 1] = run;          run += v1;
        if (base + 2 < NDST) rowptr[base + 2] = run;          run += v2;
        if (base + 3 < NDST) rowptr[base + 3] = run;
    }
}

__global__ __launch_bounds__(256) void scanB(int* __restrict__ bsum, int nb)
{
    __shared__ int sd[256];
    int t = threadIdx.x;
    int v = (t < nb) ? bsum[t] : 0;
    sd[t] = v;
    __syncthreads();
    for (int off = 1; off < 256; off <<= 1) {
        int x = 0;
        if (t >= off) x = sd[t - off];
        __syncthreads();
        if (t >= off) sd[t] += x;
        __syncthreads();
    }
    if (t < nb) bsum[t] = sd[t] - v;
}

// ---------------- prep3: scanC + attnprojA + attnprojC1 ----------------
struct Prep3 { int* rowptr; const int* bsum; int* cursor;
               const float* ts_x; const float* effT; const float* biasT; float* attnT;
               const float* e0; const float* e1; const float* e2; const float* e3;
               const float* effC; const float* biasC; float* attnC; };

__global__ __launch_bounds__(256) void prep3_k(Prep3 a)
{
    int bx = blockIdx.x;
    if (bx < 229) {
        int t = threadIdx.x;
        int off = a.bsum[bx];
        int base = bx * 1024 + t * 4;
#pragma unroll
        for (int j = 0; j < 4; j++) {
            int i = base + j;
            if (i < NDST) {
                int r = a.rowptr[i] + off;
                a.rowptr[i] = r;
                a.cursor[i] = r;
            }
        }
        if (bx == 0 && t == 0) a.rowptr[NDST] = 8 * E_N;
    } else if (bx < 425) {
        int n = (bx - 229) * 256 + threadIdx.x;
        if (n >= 50000) return;
        float acc[32];
#pragma unroll
        for (int j = 0; j < 32; j++) acc[j] = a.biasT[j];
        const float* xr = a.ts_x + (size_t)n * 64;
        for (int k = 0; k < 64; k += 4) {
            float4 xv = *(const float4*)(xr + k);
#pragma unroll
            for (int j = 0; j < 32; j++)
                acc[j] += xv.x * a.effT[(k + 0) * 32 + j] + xv.y * a.effT[(k + 1) * 32 + j]
                        + xv.z * a.effT[(k + 2) * 32 + j] + xv.w * a.effT[(k + 3) * 32 + j];
        }
#pragma unroll
        for (int j = 0; j < 32; j++) a.attnT[(size_t)n * 32 + j] = acc[j];
    } else {
        int m = (bx - 425) * 256 + threadIdx.x;
        if (m >= 34000) return;
        int q, loc;
        if (m < 1000)       { q = 0; loc = m; }
        else if (m < 21000) { q = 1; loc = m - 1000; }
        else if (m < 26000) { q = 2; loc = m - 21000; }
        else                { q = 3; loc = m - 26000; }
        const float* er = (q == 0 ? a.e0 : q == 1 ? a.e1 : q == 2 ? a.e2 : a.e3) + (size_t)loc * 128;
        const float* W = a.effC + q * 1024;
        float acc[8];
#pragma unroll
        for (int j = 0; j < 8; j++) acc[j] = a.biasC[q * 8 + j];
        for (int k = 0; k < 128; k += 4) {
            float4 xv = *(const float4*)(er + k);
#pragma unroll
            for (int j = 0; j < 8; j++)
                acc[j] += xv.x * W[(k + 0) * 8 + j] + xv.y * W[(k + 1) * 8 + j]
                        + xv.z * W[(k + 2) * 8 + j] + xv.w * W[(k + 3) * 8 + j];
        }
#pragma unroll
        for (int j = 0; j < 8; j++) a.attnC[(size_t)m * 8 + j] = acc[j];
    }
}

// ---------------- projplace: proj GEMMs + CSR place + L1 logit bake (independent) ----
struct ProjPlace { MBatch mb; EI8 ei; int* cursor; int* ssrc; int* sdst; float* exf;
                   const float* attnT; const float* attnC; };

__global__ __launch_bounds__(256, 2) void projplace_k(ProjPlace a)
{
    if (blockIdx.x < 3920) {
        gemm_body(a.mb.j[blockIdx.x / 784], blockIdx.x % 784);
    } else {
        int g = (blockIdx.x - 3920) * 256 + threadIdx.x;
        if (g >= 8 * E_N) return;
        int t = g / E_N;
        int i = g - t * E_N;
        int d = a.ei.p[t][E_N + i];
        int s = a.ei.p[t][i];
        int pos = atomicAdd(&a.cursor[c_tbase[t] + d], 1);
        a.ssrc[pos] = s;
        a.sdst[pos] = d;
        int q = t >> 1;
        float4 ex;
        if ((t & 1) == 0) {   // ts -> compact
            int w = c_co4[q] + d;
            int soff = 4 * q;
            ex.x = __expf(lrelu(a.attnT[(size_t)s * 32 + soff + 0] + a.attnC[(size_t)w * 8 + 4]));
            ex.y = __expf(lrelu(a.attnT[(size_t)s * 32 + soff + 1] + a.attnC[(size_t)w * 8 + 5]));
            ex.z = __expf(lrelu(a.attnT[(size_t)s * 32 + soff + 2] + a.attnC[(size_t)w * 8 + 6]));
            ex.w = __expf(lrelu(a.attnT[(size_t)s * 32 + soff + 3] + a.attnC[(size_t)w * 8 + 7]));
        } else {              // compact -> ts
            int m = c_co4[q] + s;
            int doff = 16 + 4 * q;
            ex.x = __expf(lrelu(a.attnC[(size_t)m * 8 + 0] + a.attnT[(size_t)d * 32 + doff + 0]));
            ex.y = __expf(lrelu(a.attnC[(size_t)m * 8 + 1] + a.attnT[(size_t)d * 32 + doff + 1]));
            ex.z = __expf(lrelu(a.attnC[(size_t)m * 8 + 2] + a.attnT[(size_t)d * 32 + doff + 2]));
            ex.w = __expf(lrelu(a.attnC[(size_t)m * 8 + 3] + a.attnT[(size_t)d * 32 + doff + 3]));
        }
        *(float4*)(a.exf + (size_t)pos * 4) = ex;
    }
}

// ---------------- agg core (exf-based, sequential-q, unroll-2) ----------------
__device__ __forceinline__ float4 agg_core(const float* __restrict__ exf,
                                           const unsigned short* __restrict__ hscbf,
                                           const int* __restrict__ rowptr,
                                           const int* __restrict__ ssrc,
                                           const float* __restrict__ bconv_l,
                                           int d, int h, int ch)
{
    const int co4[4] = {0, 1000, 21000, 26000};
    const int tb4[4] = {1000, 71000, 126000, 184000};
    const int bo4[4] = {256, 768, 1280, 1792};
    float ax = 0.f, ay = 0.f, az = 0.f, aw = 0.f;
#pragma unroll
    for (int q = 0; q < 4; q++) {
        int r0 = rowptr[tb4[q] + d], r1 = rowptr[tb4[q] + d + 1];
        float den = 0.f, sx = 0.f, sy = 0.f, sz = 0.f, sw = 0.f;
        int e = r0;
        for (; e + 2 <= r1; e += 2) {
            int sA = ssrc[e], sB = ssrc[e + 1];
            float xA = exf[(size_t)e * 4 + h];
            float xB = exf[(size_t)(e + 1) * 4 + h];
            ushort4 rA = *(const ushort4*)(hscbf + (size_t)(co4[q] + sA) * 256 + ch);
            ushort4 rB = *(const ushort4*)(hscbf + (size_t)(co4[q] + sB) * 256 + ch);
            den += xA + xB;
            sx += xA * bf2f(rA.x) + xB * bf2f(rB.x);
            sy += xA * bf2f(rA.y) + xB * bf2f(rB.y);
            sz += xA * bf2f(rA.z) + xB * bf2f(rB.z);
            sw += xA * bf2f(rA.w) + xB * bf2f(rB.w);
        }
        if (e < r1) {
            int s = ssrc[e];
            float x = exf[(size_t)e * 4 + h];
            den += x;
            ushort4 hv = *(const ushort4*)(hscbf + (size_t)(co4[q] + s) * 256 + ch);
            sx += x * bf2f(hv.x); sy += x * bf2f(hv.y);
            sz += x * bf2f(hv.z); sw += x * bf2f(hv.w);
        }
        const float* b = bconv_l + bo4[q] + ch;
        float inv = 1.f / (den + 1e-16f);
        ax += b[0] + sx * inv; ay += b[1] + sy * inv;
        az += b[2] + sz * inv; aw += b[3] + sw * inv;
    }
    float4 o;
    o.x = fmaxf(ax, 0.f); o.y = fmaxf(ay, 0.f);
    o.z = fmaxf(az, 0.f); o.w = fmaxf(aw, 0.f);
    return o;
}

// ---------------- aggx: ts->compact aggregate-first (standalone, no LDS) -------------
__global__ __launch_bounds__(256) void aggx_k(const float* __restrict__ exf,
                                              const unsigned short* __restrict__ xtsbf,
                                              const int* __restrict__ rowptr,
                                              const int* __restrict__ ssrc,
                                              float* __restrict__ aggx)
{
    int w = blockIdx.x * 4 + (threadIdx.x >> 6);   // 0..33999 (grid 8500)
    int lane = threadIdx.x & 63;
    int h = lane >> 4;
    int ch = (h << 6) | ((lane & 15) << 2);
    int q, dloc;
    if (w < 1000)       { q = 0; dloc = w; }
    else if (w < 21000) { q = 1; dloc = w - 1000; }
    else if (w < 26000) { q = 2; dloc = w - 21000; }
    else                { q = 3; dloc = w - 26000; }
    const int csr4[4] = {0, 51000, 121000, 176000};
    int r0 = rowptr[csr4[q] + dloc], r1 = rowptr[csr4[q] + dloc + 1];
    float den = 0.f, sx = 0.f, sy = 0.f, sz = 0.f, sw = 0.f;
    int e = r0;
    for (; e + 4 <= r1; e += 4) {
        int sA = ssrc[e], sB = ssrc[e + 1], sC = ssrc[e + 2], sD = ssrc[e + 3];
        float xA = exf[(size_t)e * 4 + h];
        float xB = exf[(size_t)(e + 1) * 4 + h];
        float xC = exf[(size_t)(e + 2) * 4 + h];
        float xD = exf[(size_t)(e + 3) * 4 + h];
        ushort4 rA = *(const ushort4*)(xtsbf + (size_t)sA * 256 + ch);
        ushort4 rB = *(const ushort4*)(xtsbf + (size_t)sB * 256 + ch);
        ushort4 rC = *(const ushort4*)(xtsbf + (size_t)sC * 256 + ch);
        ushort4 rD = *(const ushort4*)(xtsbf + (size_t)sD * 256 + ch);
        den += (xA + xB) + (xC + xD);
        sx += xA * bf2f(rA.x) + xB * bf2f(rB.x) + xC * bf2f(rC.x) + xD * bf2f(rD.x);
        sy += xA * bf2f(rA.y) + xB * bf2f(rB.y) + xC * bf2f(rC.y) + xD * bf2f(rD.y);
        sz += xA * bf2f(rA.z) + xB * bf2f(rB.z) + xC * bf2f(rC.z) + xD * bf2f(rD.z);
        sw += xA * bf2f(rA.w) + xB * bf2f(rB.w) + xC * bf2f(rC.w) + xD * bf2f(rD.w);
    }
    for (; e < r1; e++) {
        int s = ssrc[e];
        float x = exf[(size_t)e * 4 + h];
        den += x;
        ushort4 rv = *(const ushort4*)(xtsbf + (size_t)s * 256 + ch);
        sx += x * bf2f(rv.x); sy += x * bf2f(rv.y);
        sz += x * bf2f(rv.z); sw += x * bf2f(rv.w);
    }
    float inv = 1.f / (den + 1e-16f);
    float4 o; o.x = sx * inv; o.y = sy * inv; o.z = sz * inv; o.w = sw * inv;
    *(float4*)(aggx + (size_t)w * 256 + ch) = o;
}

// ---------------- fold: L1 ts-agg + attnT_L2 fold (standalone, 4 KB LDS) -------------
__global__ __launch_bounds__(256) void fold_k(float* __restrict__ attnT,
                                              const float* __restrict__ exf,
                                              const unsigned short* __restrict__ hscbf,
                                              const int* __restrict__ rowptr,
                                              const int* __restrict__ ssrc,
                                              const float* __restrict__ bconv_l,
                                              const float* __restrict__ weff2)
{
    int wv = threadIdx.x >> 6;
    int d = blockIdx.x * 4 + wv;                  // grid 12500
    int lane = threadIdx.x & 63;
    int h = lane >> 4;
    int ch = (h << 6) | ((lane & 15) << 2);
    float4 o = agg_core(exf, hscbf, rowptr, ssrc, bconv_l, d, h, ch);
    __shared__ float rowbuf[4][256];
    rowbuf[wv][ch + 0] = o.x; rowbuf[wv][ch + 1] = o.y;
    rowbuf[wv][ch + 2] = o.z; rowbuf[wv][ch + 3] = o.w;
    __syncthreads();
    int j = lane & 15, seg = lane >> 4;
    const float* rb = rowbuf[wv] + seg * 64;
    const float* w2 = weff2 + (seg * 64) * 32 + 16 + j;
    float s = 0.f;
#pragma unroll 8
    for (int c = 0; c < 64; c++) s += rb[c] * w2[c * 32];
    s += __shfl_xor(s, 16);
    s += __shfl_xor(s, 32);
    if (lane < 16) attnT[(size_t)d * 32 + 16 + lane] = s;
}

// ---------------- l2a: L2 GEMM (x1 -> hscbf) + attnprojC2 (x1 -> attnC) --------------
struct L2A { MBatch mb; const float* x1; const float* weff2; float* attnC; };

__global__ __launch_bounds__(256, 2) void l2a_k(L2A a)
{
    if (blockIdx.x < 1280) {
        gemm_body(a.mb.j[blockIdx.x / 320], blockIdx.x % 320);
        return;
    }
    int m = (blockIdx.x - 1280) * 256 + threadIdx.x;
    if (m >= 34000) return;
    int n = 50000 + m;
    int nt = (n < 51000) ? 1 : (n < 71000) ? 2 : (n < 76000) ? 3 : 4;
    const float* xrow = a.x1 + (size_t)n * 256;
    const float* W = a.weff2 + nt * 8192;
    float acc[8];
#pragma unroll
    for (int j = 0; j < 8; j++) acc[j] = 0.f;
    for (int k = 0; k < 256; k += 4) {
        const float4 xv = *(const float4*)(xrow + k);
#pragma unroll
        for (int j = 0; j < 8; j++)
            acc[j] += xv.x * W[(k + 0) * 32 + j] + xv.y * W[(k + 1) * 32 + j]
                    + xv.z * W[(k + 2) * 32 + j] + xv.w * W[(k + 3) * 32 + j];
    }
#pragma unroll
    for (int j = 0; j < 8; j++) a.attnC[(size_t)m * 8 + j] = acc[j];
}

// ---------------- bake_k: L2 logits for odd-type slots ----------------
__global__ __launch_bounds__(256) void bake_k(const int* __restrict__ ssrc,
                                              const int* __restrict__ sdst,
                                              const float* __restrict__ attnC,
                                              const float* __restrict__ attnT,
                                              float* __restrict__ exf)
{
    int i = blockIdx.x * 256 + threadIdx.x;
    if (i >= 400000) return;
    int tq = i / E_N;
    int i2 = i - tq * E_N;
    int e = (2 * tq + 1) * E_N + i2;
    int s = ssrc[e], d = sdst[e];
    int m = c_co4[tq] + s;
    int doff = 16 + 4 * tq;
    float4 ex;
    ex.x = __expf(lrelu(attnC[(size_t)m * 8 + 0] + attnT[(size_t)d * 32 + doff + 0]));
    ex.y = __expf(lrelu(attnC[(size_t)m * 8 + 1] + attnT[(size_t)d * 32 + doff + 1]));
    ex.z = __expf(lrelu(attnC[(size_t)m * 8 + 2] + attnT[(size_t)d * 32 + doff + 2]));
    ex.w = __expf(lrelu(attnC[(size_t)m * 8 + 3] + attnT[(size_t)d * 32 + doff + 3]));
    *(float4*)(exf + (size_t)e * 4) = ex;
}

// ---------------- pool: L2 aggregation + per-block partial ----------------
__global__ __launch_bounds__(256) void pool_k(const float* __restrict__ exf,
                                              const unsigned short* __restrict__ hscbf,
                                              const int* __restrict__ rowptr,
                                              const int* __restrict__ ssrc,
                                              const float* __restrict__ bconv_l,
                                              float* __restrict__ part)
{
    int d = blockIdx.x * 4 + (threadIdx.x >> 6);
    int lane = threadIdx.x & 63;
    int h = lane >> 4;
    int ch = (h << 6) | ((lane & 15) << 2);
    float4 o = agg_core(exf, hscbf, rowptr, ssrc, bconv_l, d, h, ch);
    __shared__ float4 red4[256];
    red4[threadIdx.x] = o;
    __syncthreads();
    if (threadIdx.x < 64) {
        float4 a = red4[threadIdx.x], b = red4[threadIdx.x + 64];
        float4 c = red4[threadIdx.x + 128], dd = red4[threadIdx.x + 192];
        float4 s;
        s.x = (a.x + b.x) + (c.x + dd.x);
        s.y = (a.y + b.y) + (c.y + dd.y);
        s.z = (a.z + b.z) + (c.z + dd.z);
        s.w = (a.w + b.w) + (c.w + dd.w);
        int cch = ((threadIdx.x >> 4) << 6) | ((threadIdx.x & 15) << 2);
        *(float4*)(part + (size_t)blockIdx.x * 256 + cch) = s;
    }
}

__global__ __launch_bounds__(256) void colsum_part(const float* __restrict__ part,
                                                   float* __restrict__ gsum)
{
    int c = threadIdx.x;
    float s = 0.f;
    for (int r = blockIdx.x; r < 12500; r += gridDim.x) s += part[(size_t)r * 256 + c];
    atomAddF(gsum + c, s);
}

__global__ __launch_bounds__(128) void head_k(const float* __restrict__ gsum,
                                              const float* __restrict__ Wc1,
                                              const float* __restrict__ bc1,
                                              const float* __restrict__ Wc2,
                                              const float* __restrict__ bc2,
                                              float* __restrict__ out)
{
    __shared__ float g[256];
    __shared__ float red[128];
    int t = threadIdx.x;
    g[t] = gsum[t] * (1.f / 50000.f);
    g[t + 128] = gsum[t + 128] * (1.f / 50000.f);
    __syncthreads();
    float acc = bc1[t];
    for (int k = 0; k < 256; k++) acc += g[k] * Wc1[k * 128 + t];
    red[t] = fmaxf(acc, 0.f) * Wc2[t];
    __syncthreads();
    for (int sft = 64; sft > 0; sft >>= 1) {
        if (t < sft) red[t] += red[t + sft];
        __syncthreads();
    }
    if (t == 0) out[0] = red[0] + bc2[0];
}

extern "C" void kernel_launch(void* const* d_in, const int* in_sizes, int n_in,
                              void* d_out, int out_size, void* d_ws, size_t ws_size,
                              hipStream_t stream)
{
    const float* ts_x   = (const float*)d_in[0];
    const float* emb[4] = {(const float*)d_in[1], (const float*)d_in[2],
                           (const float*)d_in[3], (const float*)d_in[4]};
    const float* Wp_ts  = (const float*)d_in[5];
    const float* bp_ts  = (const float*)d_in[6];
    const float* Wp_c   = (const float*)d_in[7];
    const float* bp_c   = (const float*)d_in[8];
    const float* Wsrc   = (const float*)d_in[9];
    const float* Wdst   = (const float*)d_in[10];
    const float* asrc   = (const float*)d_in[11];
    const float* adst   = (const float*)d_in[12];
    const float* bconv  = (const float*)d_in[13];
    const float* Wc1    = (const float*)d_in[14];
    const float* bc1    = (const float*)d_in[15];
    const float* Wc2    = (const float*)d_in[16];
    const float* bc2    = (const float*)d_in[17];
    EI8 ei;
    for (int t = 0; t < 8; t++) ei.p[t] = (const int*)d_in[18 + t];

    // workspace layout (float units)
    float* x0    = (float*)d_ws;            // 21,504,000 (ts region reused: exf/sdst/part)
    float* x1    = x0    + 21504000;        // 21,504,000 (ts region = aggx; compact = L2 input)
    float* attnT = x1    + 21504000;        // 1,600,000
    float* attnC = attnT + 1600000;         // 272,000 (L1, reused for L2)
    float* weff  = attnC + 272000;          // 81,920
    float* gsum  = weff  + 81920;           // 256
    float* effT  = gsum  + 256;             // 2,048
    float* biasT = effT  + 2048;            // 32
    float* effC  = biasT + 32;              // 4,096
    float* biasC = effC  + 4096;            // 32
    int* rowptr  = (int*)(biasC + 32);      // 234,004
    int* bsum    = rowptr + 234004;         // 256
    int* ssrc    = bsum + 256;              // 800,000
    unsigned short* xtsbf = (unsigned short*)(ssrc + 800000);   // 12,800,000 us
    unsigned short* hscbf = xtsbf + 12800000;                   //  8,704,000 us
    unsigned short* btp   = hscbf + 8704000;                    //  1,867,776 us
    int* cursor  = (int*)hscbf;             // alias: CSR build finishes before hscbf used
    float* aggx  = x1;                      // alias x1 ts region (rows 0..33999)
    float* exf   = x0;                      // 3,200,000
    int* sdst    = (int*)(x0 + 3200000);    // 800,000
    float* part  = x0 + 4200000;            // 3,200,000

    unsigned short* bt_ts_h = btp;
    unsigned short* bt_ts_l = bt_ts_h + 16384;
    unsigned short* bt_c_h[4], *bt_c_l[4];
    {
        unsigned short* p = bt_ts_l + 16384;
        for (int q = 0; q < 4; q++) { bt_c_h[q] = p; p += 32768; bt_c_l[q] = p; p += 32768; }
    }
    unsigned short* bt_w = bt_ts_l + 16384 + 8 * 32768;
    auto wpan_h = [&](int l, int t) { return bt_w + (size_t)((l == 0 ? t : 8 + t / 2) * 2) * 65536; };
    auto wpan_l = [&](int l, int t) { return wpan_h(l, t) + 65536; };

    static const int Nd4[4]    = {1000, 20000, 5000, 8000};
    static const int co4[4]    = {0, 1000, 21000, 26000};
    static const int dbase4[4] = {50000, 51000, 71000, 76000};
    static const int tsrc[4]   = {1, 3, 5, 7};
    static const int tdst[4]   = {0, 2, 4, 6};

    hipMemsetAsync(cursor, 0, NDST * sizeof(int), stream);

    // ---- prep1: makeBT + fill_weff + count ----
    {
        Prep1 a = {};
        int zi = 0;
        a.bt.j[zi++] = {Wp_ts, bt_ts_h, bt_ts_l, 64, 6};
        for (int q = 0; q < 4; q++)
            a.bt.j[zi++] = {Wp_c + q * 32768, bt_c_h[q], bt_c_l[q], 128, 7};
        for (int t = 0; t < 8; t++)
            a.bt.j[zi++] = {Wsrc + (size_t)(0 * 8 + t) * 65536, wpan_h(0, t), wpan_l(0, t), 256, 8};
        for (int t = 1; t < 8; t += 2)
            a.bt.j[zi++] = {Wsrc + (size_t)(1 * 8 + t) * 65536, wpan_h(1, t), wpan_l(1, t), 256, 8};
        a.Wsrc = Wsrc; a.Wdst = Wdst; a.asrc = asrc; a.adst = adst;
        a.weff = weff; a.ei = ei; a.cnt = cursor;
        prep1_k<<<7797, 256, 0, stream>>>(a);
    }

    // ---- prep2 + scanB + prep3 ----
    prep2_k<<<254, 256, 0, stream>>>(Wp_ts, bp_ts, Wp_c, bp_c, weff,
                                     effT, biasT, effC, biasC, cursor, rowptr, bsum);
    scanB<<<1, 256, 0, stream>>>(bsum, 229);
    {
        Prep3 a = {rowptr, bsum, cursor, ts_x, effT, biasT, attnT,
                   emb[0], emb[1], emb[2], emb[3], effC, biasC, attnC};
        prep3_k<<<558, 256, 0, stream>>>(a);
    }

    // ---- projplace: input projections + CSR place + L1 logit bake ----
    {
        ProjPlace a = {};
        a.mb.j[0] = {ts_x, bt_ts_h, bt_ts_l, nullptr, xtsbf, bp_ts, 50000, 64, 0};
        for (int q = 0; q < 4; q++)
            a.mb.j[1 + q] = {emb[q], bt_c_h[q], bt_c_l[q], x0 + (size_t)dbase4[q] * 256,
                             nullptr, bp_c + q * 256, Nd4[q], 128, 0};
        a.ei = ei; a.cursor = cursor; a.ssrc = ssrc; a.sdst = sdst; a.exf = exf;
        a.attnT = attnT; a.attnC = attnC;
        projplace_k<<<7045, 256, 0, stream>>>(a);
    }

    // ---- aggx (standalone, high occupancy) ----
    aggx_k<<<8500, 256, 0, stream>>>(exf, xtsbf, rowptr, ssrc, aggx);

    // ---- L1 GEMM batch: all 8 jobs (x0->hscbf, aggx->x1) ----
    {
        MBatch b = {};
        for (int q = 0; q < 4; q++)
            b.j[q] = {x0 + (size_t)dbase4[q] * 256, wpan_h(0, tsrc[q]), wpan_l(0, tsrc[q]),
                      nullptr, hscbf + (size_t)co4[q] * 256, nullptr, Nd4[q], 256, 0};
        for (int q = 0; q < 4; q++)
            b.j[4 + q] = {aggx + (size_t)co4[q] * 256, wpan_h(0, tdst[q]), wpan_l(0, tdst[q]),
                          x1 + (size_t)dbase4[q] * 256, nullptr, bconv + tdst[q] * 256, Nd4[q], 256, 1};
        gemm_mb<<<2560, 256, 0, stream>>>(b);
    }

    // ---- fold (standalone, 4 KB LDS, high occupancy) ----
    fold_k<<<12500, 256, 0, stream>>>(attnT, exf, hscbf, rowptr, ssrc, bconv, weff + 40960);

    // ---- l2a: L2 GEMM + attnprojC2 ----
    {
        L2A a = {};
        for (int q = 0; q < 4; q++)
            a.mb.j[q] = {x1 + (size_t)dbase4[q] * 256, wpan_h(1, tsrc[q]), wpan_l(1, tsrc[q]),
                         nullptr, hscbf + (size_t)co4[q] * 256, nullptr, Nd4[q], 256, 0};
        a.x1 = x1; a.weff2 = weff + 40960; a.attnC = attnC;
        l2a_k<<<1413, 256, 0, stream>>>(a);
    }

    // ---- bake L2 logits, then pool + reduce + head ----
    bake_k<<<1563, 256, 0, stream>>>(ssrc, sdst, attnC, attnT, exf);
    hipMemsetAsync(gsum, 0, 256 * sizeof(float), stream);
    pool_k<<<12500, 256, 0, stream>>>(exf, hscbf, rowptr, ssrc, bconv + 2048, part);
    colsum_part<<<256, 256, 0, stream>>>(part, gsum);
    head_k<<<1, 128, 0, stream>>>(gsum, Wc1, bc1, Wc2, bc2, (float*)d_out);
}